// Round 1
// baseline (3693.494 us; speedup 1.0000x reference)
//
#include <hip/hip_runtime.h>
#include <math.h>

// Dims (fixed by the problem)
#define T_ 256
#define F_ 256
#define B_ 64      // C*N
#define H_ 8
#define HD_ 32
#define E_ 1024
#define D_ 262144  // T*F*C
#define N_ 16
#define M_ 16384   // B_*T_ tokens

// ---------------------------------------------------------------- build h ---
// h[(c*16+n)*T*F + t*F + f] = x[((n*F+f)*T+t)*C + c] + t/255
__global__ __launch_bounds__(256) void build_h(const float* __restrict__ x,
                                               float* __restrict__ h) {
    int idx = blockIdx.x * 256 + threadIdx.x;   // < 64*256*256
    int f = idx & 255;
    int t = (idx >> 8) & 255;
    int b = idx >> 16;
    int c = b >> 4;
    int n = b & 15;
    h[idx] = x[((n * 256 + f) * 256 + t) * 4 + c] + (float)t * (1.0f / 255.0f);
}

// ---------------------------------------------------------------- attention ---
// One block per (b, head). Fused QKV projection + flash softmax + o write.
// LDS exactly 64 KB: k,v rows (write conflicts are one-time; reads are broadcast).
__global__ __launch_bounds__(256) void attn_kernel(const float* __restrict__ h,
                                                   const float* __restrict__ Wq,
                                                   const float* __restrict__ Wk,
                                                   const float* __restrict__ Wv,
                                                   float* __restrict__ o) {
    __shared__ float ks[256][32];
    __shared__ float vs[256][32];
    const int b = blockIdx.x >> 3;
    const int hh = blockIdx.x & 7;
    const int t = threadIdx.x;

    const float* zp = h + (b * 256 + t) * 256 + hh * 32;
    float z[32];
#pragma unroll
    for (int e4 = 0; e4 < 8; ++e4) {
        float4 tv = *(const float4*)(zp + e4 * 4);
        z[e4 * 4 + 0] = tv.x; z[e4 * 4 + 1] = tv.y;
        z[e4 * 4 + 2] = tv.z; z[e4 * 4 + 3] = tv.w;
    }

    float q[32];
#pragma unroll
    for (int dg = 0; dg < 8; ++dg) {
        float4 k4, v4;
#pragma unroll
        for (int di = 0; di < 4; ++di) {
            const int d = dg * 4 + di;
            const float* wq = Wq + d * 32;
            const float* wk = Wk + d * 32;
            const float* wv = Wv + d * 32;
            float qd = 0.f, kd = 0.f, vd = 0.f;
#pragma unroll
            for (int e = 0; e < 32; ++e) {
                qd += z[e] * wq[e];
                kd += z[e] * wk[e];
                vd += z[e] * wv[e];
            }
            q[d] = qd * 0.0625f;      // scale = 1/sqrt(F=256)
            (&k4.x)[di] = kd;
            (&v4.x)[di] = vd;
        }
        *(float4*)&ks[t][dg * 4] = k4;
        *(float4*)&vs[t][dg * 4] = v4;
    }
    __syncthreads();

    // flash-style online softmax over 256 keys
    float m = -1e30f, lsum = 0.f;
    float oacc[32];
#pragma unroll
    for (int e = 0; e < 32; ++e) oacc[e] = 0.f;

    for (int j = 0; j < 256; ++j) {
        const float4* kp = (const float4*)&ks[j][0];
        float s = 0.f;
#pragma unroll
        for (int e4 = 0; e4 < 8; ++e4) {
            float4 kv = kp[e4];
            s += q[e4 * 4 + 0] * kv.x + q[e4 * 4 + 1] * kv.y +
                 q[e4 * 4 + 2] * kv.z + q[e4 * 4 + 3] * kv.w;
        }
        float mn = fmaxf(m, s);
        float alpha = __expf(m - mn);
        float p = __expf(s - mn);
        lsum = lsum * alpha + p;
        const float4* vp = (const float4*)&vs[j][0];
#pragma unroll
        for (int e4 = 0; e4 < 8; ++e4) {
            float4 vv = vp[e4];
            oacc[e4 * 4 + 0] = oacc[e4 * 4 + 0] * alpha + p * vv.x;
            oacc[e4 * 4 + 1] = oacc[e4 * 4 + 1] * alpha + p * vv.y;
            oacc[e4 * 4 + 2] = oacc[e4 * 4 + 2] * alpha + p * vv.z;
            oacc[e4 * 4 + 3] = oacc[e4 * 4 + 3] * alpha + p * vv.w;
        }
        m = mn;
    }
    const float inv = 1.0f / lsum;
    float* op = o + (b * 256 + t) * 256 + hh * 32;
#pragma unroll
    for (int e4 = 0; e4 < 8; ++e4) {
        float4 ov;
        ov.x = oacc[e4 * 4 + 0] * inv; ov.y = oacc[e4 * 4 + 1] * inv;
        ov.z = oacc[e4 * 4 + 2] * inv; ov.w = oacc[e4 * 4 + 3] * inv;
        *(float4*)(op + e4 * 4) = ov;
    }
}

// ---------------------------------------------------------------- fp32 GEMM ---
// C[M,Nn] = A[M,K] @ W[Nn,K]^T + bias (+relu). 128x128 tile, 8x8 per thread.
__global__ __launch_bounds__(256) void gemm_bias(const float* __restrict__ A,
                                                 const float* __restrict__ W,
                                                 const float* __restrict__ bias,
                                                 float* __restrict__ C,
                                                 int M, int Nn, int K, int doRelu) {
    __shared__ float As[16][132];
    __shared__ float Ws[16][132];
    const int tid = threadIdx.x;
    const int tr = tid >> 4, tc = tid & 15;
    const int row0 = blockIdx.y * 128, col0 = blockIdx.x * 128;

    float acc[8][8];
#pragma unroll
    for (int i = 0; i < 8; ++i)
#pragma unroll
        for (int j = 0; j < 8; ++j) acc[i][j] = 0.f;

    for (int k0 = 0; k0 < K; k0 += 16) {
#pragma unroll
        for (int jj = 0; jj < 8; ++jj) {
            int i = jj * 256 + tid;
            int mI = i >> 4, kI = i & 15;
            As[kI][mI] = A[(row0 + mI) * K + k0 + kI];
            Ws[kI][mI] = W[(col0 + mI) * K + k0 + kI];
        }
        __syncthreads();
#pragma unroll
        for (int kk = 0; kk < 16; ++kk) {
            float4 a0 = *(const float4*)&As[kk][tr * 8];
            float4 a1 = *(const float4*)&As[kk][tr * 8 + 4];
            float4 w0 = *(const float4*)&Ws[kk][tc * 8];
            float4 w1 = *(const float4*)&Ws[kk][tc * 8 + 4];
            float av[8] = {a0.x, a0.y, a0.z, a0.w, a1.x, a1.y, a1.z, a1.w};
            float wv[8] = {w0.x, w0.y, w0.z, w0.w, w1.x, w1.y, w1.z, w1.w};
#pragma unroll
            for (int i2 = 0; i2 < 8; ++i2)
#pragma unroll
                for (int j2 = 0; j2 < 8; ++j2) acc[i2][j2] += av[i2] * wv[j2];
        }
        __syncthreads();
    }

    float bcol[8];
#pragma unroll
    for (int j2 = 0; j2 < 8; ++j2) bcol[j2] = bias[col0 + tc * 8 + j2];
#pragma unroll
    for (int i2 = 0; i2 < 8; ++i2) {
        int row = row0 + tr * 8 + i2;
        float4 o0, o1;
        float v0 = acc[i2][0] + bcol[0], v1 = acc[i2][1] + bcol[1];
        float v2 = acc[i2][2] + bcol[2], v3 = acc[i2][3] + bcol[3];
        float v4 = acc[i2][4] + bcol[4], v5 = acc[i2][5] + bcol[5];
        float v6 = acc[i2][6] + bcol[6], v7 = acc[i2][7] + bcol[7];
        if (doRelu) {
            v0 = fmaxf(v0, 0.f); v1 = fmaxf(v1, 0.f); v2 = fmaxf(v2, 0.f);
            v3 = fmaxf(v3, 0.f); v4 = fmaxf(v4, 0.f); v5 = fmaxf(v5, 0.f);
            v6 = fmaxf(v6, 0.f); v7 = fmaxf(v7, 0.f);
        }
        o0.x = v0; o0.y = v1; o0.z = v2; o0.w = v3;
        o1.x = v4; o1.y = v5; o1.z = v6; o1.w = v7;
        *(float4*)&C[row * Nn + col0 + tc * 8] = o0;
        *(float4*)&C[row * Nn + col0 + tc * 8 + 4] = o1;
    }
}

// ------------------------------------------------------ residual + layernorm ---
__global__ __launch_bounds__(256) void ln_residual(const float* __restrict__ A,
                                                   const float* __restrict__ R,
                                                   const float* __restrict__ g,
                                                   const float* __restrict__ b,
                                                   float* __restrict__ O) {
    const int row = blockIdx.x;
    const int tid = threadIdx.x;
    float v = A[row * 256 + tid] + R[row * 256 + tid];
    float s = v, sq = v * v;
#pragma unroll
    for (int off = 32; off > 0; off >>= 1) {
        s += __shfl_down(s, off, 64);
        sq += __shfl_down(sq, off, 64);
    }
    __shared__ float ss[4], ssq[4];
    const int wave = tid >> 6, lane = tid & 63;
    if (lane == 0) { ss[wave] = s; ssq[wave] = sq; }
    __syncthreads();
    float S = ss[0] + ss[1] + ss[2] + ss[3];
    float SQ = ssq[0] + ssq[1] + ssq[2] + ssq[3];
    float mean = S * (1.0f / 256.0f);
    float var = SQ * (1.0f / 256.0f) - mean * mean;
    float inv = rsqrtf(var + 1e-5f);
    O[row * 256 + tid] = (v - mean) * inv * g[tid] + b[tid];
}

// ---------------------------------------------------------------- head GEMM ---
// z[head][n][j] = sum_d flat[n,d] * W1[j,d]; flat gathered from h on the fly.
// Grid 512 = 128 j-tiles (4 j each, both heads concatenated) x 4 d-chunks.
__global__ __launch_bounds__(256) void head_gemm(const float* __restrict__ h,
                                                 const float* __restrict__ eW1,
                                                 const float* __restrict__ aW1,
                                                 float* __restrict__ zraw) {
    const int bx = blockIdx.x;
    const int jt = bx >> 2;        // 0..127
    const int chunk = bx & 3;
    const int jj0 = jt * 4;        // 0..508
    const int head = jj0 >> 8;
    const int jl0 = jj0 & 255;
    const float* W = (head ? aW1 : eW1) + (size_t)jl0 * D_;
    const int tid = threadIdx.x;

    float acc[4][16];
#pragma unroll
    for (int jb = 0; jb < 4; ++jb)
#pragma unroll
        for (int n = 0; n < 16; ++n) acc[jb][n] = 0.f;

    for (int s = 0; s < 64; ++s) {
        const int d4 = chunk * 65536 + s * 1024 + tid * 4;
        const int tf = d4 >> 2;     // = t*F + f
        float4 wv[4];
#pragma unroll
        for (int jb = 0; jb < 4; ++jb)
            wv[jb] = *(const float4*)(W + (size_t)jb * D_ + d4);
#pragma unroll
        for (int c = 0; c < 4; ++c) {
            const float* hp = h + c * 1048576 + tf;
            float fl[16];
#pragma unroll
            for (int n = 0; n < 16; ++n) fl[n] = hp[n * 65536];
#pragma unroll
            for (int jb = 0; jb < 4; ++jb) {
                const float w = (&wv[jb].x)[c];
#pragma unroll
                for (int n = 0; n < 16; ++n) acc[jb][n] += w * fl[n];
            }
        }
    }

    const int lane = tid & 63;
#pragma unroll
    for (int jb = 0; jb < 4; ++jb) {
#pragma unroll
        for (int n = 0; n < 16; ++n) {
            float v = acc[jb][n];
            v += __shfl_down(v, 32, 64);
            v += __shfl_down(v, 16, 64);
            v += __shfl_down(v, 8, 64);
            v += __shfl_down(v, 4, 64);
            v += __shfl_down(v, 2, 64);
            v += __shfl_down(v, 1, 64);
            if (lane == 0)
                atomicAdd(&zraw[head * 4096 + n * 256 + jl0 + jb], v);
        }
    }
}

__global__ __launch_bounds__(256) void zero_kernel(float* __restrict__ p) {
    p[blockIdx.x * 256 + threadIdx.x] = 0.f;
}

// ---------------------------------------------------------------- head MLP ---
// One block per sample n. bn + relu -> 256x256 relu -> 256x256 relu -> W4 -> clip.
__global__ __launch_bounds__(256) void mlp_head(const float* __restrict__ zr,
                                                const float* __restrict__ b1,
                                                const float* __restrict__ g,
                                                const float* __restrict__ bt,
                                                const float* __restrict__ W2,
                                                const float* __restrict__ b2,
                                                const float* __restrict__ W3,
                                                const float* __restrict__ b3,
                                                const float* __restrict__ W4,
                                                float* __restrict__ out,
                                                float lo, float hi, int coff) {
    __shared__ float za[256], zb[256];
    const int n = blockIdx.x, j = threadIdx.x;
    float z = zr[n * 256 + j] + b1[j];
    z = z * 0.99999500003749969f * g[j] + bt[j];   // 1/sqrt(1+1e-5)
    za[j] = fmaxf(z, 0.f);
    __syncthreads();
    float a = b2[j];
    for (int e = 0; e < 256; ++e) a += za[e] * W2[j * 256 + e];
    zb[j] = fmaxf(a, 0.f);
    __syncthreads();
    a = b3[j];
    for (int e = 0; e < 256; ++e) a += zb[e] * W3[j * 256 + e];
    za[j] = fmaxf(a, 0.f);     // safe: all za reads finished before prev barrier
    __syncthreads();
    if (j < 2) {
        float v = 0.f;
        for (int e = 0; e < 256; ++e) v += za[e] * W4[j * 256 + e];
        v = fminf(fmaxf(v, lo), hi);
        out[n * 4 + 2 * j + coff] = v;
    }
}

// ---------------------------------------------------------------- launcher ---
extern "C" void kernel_launch(void* const* d_in, const int* in_sizes, int n_in,
                              void* d_out, int out_size, void* d_ws, size_t ws_size,
                              hipStream_t stream) {
    const float* x     = (const float*)d_in[0];
    const float* Wq    = (const float*)d_in[1];
    const float* Wk    = (const float*)d_in[2];
    const float* Wv    = (const float*)d_in[3];
    const float* Wo    = (const float*)d_in[4];
    const float* bo    = (const float*)d_in[5];
    const float* ln1g  = (const float*)d_in[6];
    const float* ln1b  = (const float*)d_in[7];
    const float* ln2g  = (const float*)d_in[8];
    const float* ln2b  = (const float*)d_in[9];
    const float* ffW1  = (const float*)d_in[10];
    const float* ffb1  = (const float*)d_in[11];
    const float* ffW2  = (const float*)d_in[12];
    const float* ffb2  = (const float*)d_in[13];
    const float* eW1   = (const float*)d_in[14];
    const float* eb1   = (const float*)d_in[15];
    const float* eg    = (const float*)d_in[16];
    const float* ebt   = (const float*)d_in[17];
    const float* eW2   = (const float*)d_in[18];
    const float* eb2   = (const float*)d_in[19];
    const float* eW3   = (const float*)d_in[20];
    const float* eb3   = (const float*)d_in[21];
    const float* eW4   = (const float*)d_in[22];
    const float* aW1   = (const float*)d_in[23];
    const float* ab1   = (const float*)d_in[24];
    const float* ag    = (const float*)d_in[25];
    const float* abt   = (const float*)d_in[26];
    const float* aW2   = (const float*)d_in[27];
    const float* ab2   = (const float*)d_in[28];
    const float* aW3   = (const float*)d_in[29];
    const float* ab3   = (const float*)d_in[30];
    const float* aW4   = (const float*)d_in[31];
    float* out = (float*)d_out;

    // workspace layout (floats): needs ~134.3 MB
    float* ws   = (float*)d_ws;
    float* h    = ws;                    // 4 Mi floats
    float* ao   = ws + 4194304;          // attention out
    float* tmp  = ws + 8388608;          // gemm out
    float* x1   = ws + 12582912;
    float* ff1  = ws + 16777216;         // 16 Mi floats
    float* zraw = ws + 33554432;         // 8192 floats

    build_h<<<16384, 256, 0, stream>>>(x, h);

    for (int l = 0; l < 6; ++l) {
        attn_kernel<<<512, 256, 0, stream>>>(h, Wq + l * 1024, Wk + l * 1024,
                                             Wv + l * 1024, ao);
        gemm_bias<<<dim3(2, 128), 256, 0, stream>>>(ao, Wo + l * 65536, bo + l * 256,
                                                    tmp, M_, 256, 256, 0);
        ln_residual<<<16384, 256, 0, stream>>>(tmp, h, ln1g + l * 256, ln1b + l * 256, x1);
        gemm_bias<<<dim3(8, 128), 256, 0, stream>>>(x1, ffW1 + l * 262144, ffb1 + l * 1024,
                                                    ff1, M_, 1024, 256, 1);
        gemm_bias<<<dim3(2, 128), 256, 0, stream>>>(ff1, ffW2 + l * 262144, ffb2 + l * 256,
                                                    tmp, M_, 256, 1024, 0);
        ln_residual<<<16384, 256, 0, stream>>>(tmp, x1, ln2g + l * 256, ln2b + l * 256, h);
    }

    zero_kernel<<<32, 256, 0, stream>>>(zraw);
    head_gemm<<<512, 256, 0, stream>>>(h, eW1, aW1, zraw);

    const float pi = 3.14159265358979323846f;
    mlp_head<<<16, 256, 0, stream>>>(zraw, eb1, eg, ebt, eW2, eb2, eW3, eb3, eW4,
                                     out, -pi / 4.f, pi / 2.f, 0);
    mlp_head<<<16, 256, 0, stream>>>(zraw + 4096, ab1, ag, abt, aW2, ab2, aW3, ab3, aW4,
                                     out, 0.f, 2.f * pi, 1);
}

// Round 2
// 2494.952 us; speedup vs baseline: 1.4804x; 1.4804x over previous
//
#include <hip/hip_runtime.h>
#include <math.h>

// Dims (fixed by the problem)
#define T_ 256
#define F_ 256
#define B_ 64      // C*N
#define H_ 8
#define HD_ 32
#define E_ 1024
#define D_ 262144  // T*F*C
#define N_ 16
#define M_ 16384   // B_*T_ tokens

typedef __attribute__((ext_vector_type(8))) short bf16x8;
typedef __attribute__((ext_vector_type(4))) float f32x4;

// ---------------------------------------------------------------- build h ---
__global__ __launch_bounds__(256) void build_h(const float* __restrict__ x,
                                               float* __restrict__ h) {
    int idx = blockIdx.x * 256 + threadIdx.x;   // < 64*256*256
    int f = idx & 255;
    int t = (idx >> 8) & 255;
    int b = idx >> 16;
    int c = b >> 4;
    int n = b & 15;
    h[idx] = x[((n * 256 + f) * 256 + t) * 4 + c] + (float)t * (1.0f / 255.0f);
}

// ---------------------------------------------------------------- attention ---
__global__ __launch_bounds__(256) void attn_kernel(const float* __restrict__ h,
                                                   const float* __restrict__ Wq,
                                                   const float* __restrict__ Wk,
                                                   const float* __restrict__ Wv,
                                                   float* __restrict__ o) {
    __shared__ float ks[256][32];
    __shared__ float vs[256][32];
    const int b = blockIdx.x >> 3;
    const int hh = blockIdx.x & 7;
    const int t = threadIdx.x;

    const float* zp = h + (b * 256 + t) * 256 + hh * 32;
    float z[32];
#pragma unroll
    for (int e4 = 0; e4 < 8; ++e4) {
        float4 tv = *(const float4*)(zp + e4 * 4);
        z[e4 * 4 + 0] = tv.x; z[e4 * 4 + 1] = tv.y;
        z[e4 * 4 + 2] = tv.z; z[e4 * 4 + 3] = tv.w;
    }

    float q[32];
#pragma unroll
    for (int dg = 0; dg < 8; ++dg) {
        float4 k4, v4;
#pragma unroll
        for (int di = 0; di < 4; ++di) {
            const int d = dg * 4 + di;
            const float* wq = Wq + d * 32;
            const float* wk = Wk + d * 32;
            const float* wv = Wv + d * 32;
            float qd = 0.f, kd = 0.f, vd = 0.f;
#pragma unroll
            for (int e = 0; e < 32; ++e) {
                qd += z[e] * wq[e];
                kd += z[e] * wk[e];
                vd += z[e] * wv[e];
            }
            q[d] = qd * 0.0625f;      // scale = 1/sqrt(F=256)
            (&k4.x)[di] = kd;
            (&v4.x)[di] = vd;
        }
        *(float4*)&ks[t][dg * 4] = k4;
        *(float4*)&vs[t][dg * 4] = v4;
    }
    __syncthreads();

    float m = -1e30f, lsum = 0.f;
    float oacc[32];
#pragma unroll
    for (int e = 0; e < 32; ++e) oacc[e] = 0.f;

    for (int j = 0; j < 256; ++j) {
        const float4* kp = (const float4*)&ks[j][0];
        float s = 0.f;
#pragma unroll
        for (int e4 = 0; e4 < 8; ++e4) {
            float4 kv = kp[e4];
            s += q[e4 * 4 + 0] * kv.x + q[e4 * 4 + 1] * kv.y +
                 q[e4 * 4 + 2] * kv.z + q[e4 * 4 + 3] * kv.w;
        }
        float mn = fmaxf(m, s);
        float alpha = __expf(m - mn);
        float p = __expf(s - mn);
        lsum = lsum * alpha + p;
        const float4* vp = (const float4*)&vs[j][0];
#pragma unroll
        for (int e4 = 0; e4 < 8; ++e4) {
            float4 vv = vp[e4];
            oacc[e4 * 4 + 0] = oacc[e4 * 4 + 0] * alpha + p * vv.x;
            oacc[e4 * 4 + 1] = oacc[e4 * 4 + 1] * alpha + p * vv.y;
            oacc[e4 * 4 + 2] = oacc[e4 * 4 + 2] * alpha + p * vv.z;
            oacc[e4 * 4 + 3] = oacc[e4 * 4 + 3] * alpha + p * vv.w;
        }
        m = mn;
    }
    const float inv = 1.0f / lsum;
    float* op = o + (b * 256 + t) * 256 + hh * 32;
#pragma unroll
    for (int e4 = 0; e4 < 8; ++e4) {
        float4 ov;
        ov.x = oacc[e4 * 4 + 0] * inv; ov.y = oacc[e4 * 4 + 1] * inv;
        ov.z = oacc[e4 * 4 + 2] * inv; ov.w = oacc[e4 * 4 + 3] * inv;
        *(float4*)(op + e4 * 4) = ov;
    }
}

// --------------------------------------------- split-bf16 MFMA GEMM -----------
// C[M,Nn] = A[M,K] @ W[Nn,K]^T + bias (+relu), fp32 in/out.
// Each fp32 value split as v = hi + lo (bf16 each, truncate-split); product via
// 3 MFMAs (lo*hi, hi*lo, hi*hi) -> ~2^-16 relative error.
// 128x128 tile, 4 waves, each wave 4x4 tiles of 16x16x32 MFMA. K-chunk 32.
#define LDST 40   // LDS row stride in shorts (padded: 80B rows, 16B-aligned)

struct GemmLds {
    short Ahi[128][LDST];
    short Alo[128][LDST];
    short Whi[128][LDST];
    short Wlo[128][LDST];
};

__device__ inline void split2(float a0, float a1, unsigned& hi, unsigned& lo) {
    unsigned u0 = __float_as_uint(a0), u1 = __float_as_uint(a1);
    hi = __builtin_amdgcn_perm(u1, u0, 0x07060302);
    float r0 = a0 - __uint_as_float(u0 & 0xffff0000u);
    float r1 = a1 - __uint_as_float(u1 & 0xffff0000u);
    lo = __builtin_amdgcn_perm(__float_as_uint(r1), __float_as_uint(r0), 0x07060302);
}

__global__ __launch_bounds__(256, 2) void gemm_mfma(const float* __restrict__ A,
                                                    const float* __restrict__ W,
                                                    const float* __restrict__ bias,
                                                    float* __restrict__ C,
                                                    int M, int Nn, int K, int doRelu) {
    __shared__ GemmLds lds;
    const int tid = threadIdx.x;
    const int row0 = blockIdx.y * 128, col0 = blockIdx.x * 128;
    const int wave = tid >> 6, lane = tid & 63;
    const int wr = wave >> 1, wc = wave & 1;      // wave origin (wr*64, wc*64)
    const int lrow = tid >> 3;                     // 0..31
    const int lcol = (tid & 7) * 4;                // 0,4,...,28

    f32x4 acc[4][4];
#pragma unroll
    for (int i = 0; i < 4; ++i)
#pragma unroll
        for (int j = 0; j < 4; ++j) acc[i][j] = (f32x4){0.f, 0.f, 0.f, 0.f};

    float4 abuf[4], wbuf[4];
#pragma unroll
    for (int jj = 0; jj < 4; ++jj) {
        abuf[jj] = *(const float4*)&A[(size_t)(row0 + jj * 32 + lrow) * K + lcol];
        wbuf[jj] = *(const float4*)&W[(size_t)(col0 + jj * 32 + lrow) * K + lcol];
    }

    for (int k0 = 0; k0 < K; k0 += 32) {
        // convert + stage to LDS
#pragma unroll
        for (int jj = 0; jj < 4; ++jj) {
            const int row = jj * 32 + lrow;
            unsigned h01, l01, h23, l23;
            split2(abuf[jj].x, abuf[jj].y, h01, l01);
            split2(abuf[jj].z, abuf[jj].w, h23, l23);
            *(uint2*)&lds.Ahi[row][lcol] = make_uint2(h01, h23);
            *(uint2*)&lds.Alo[row][lcol] = make_uint2(l01, l23);
            split2(wbuf[jj].x, wbuf[jj].y, h01, l01);
            split2(wbuf[jj].z, wbuf[jj].w, h23, l23);
            *(uint2*)&lds.Whi[row][lcol] = make_uint2(h01, h23);
            *(uint2*)&lds.Wlo[row][lcol] = make_uint2(l01, l23);
        }
        __syncthreads();

        // prefetch next chunk while MFMAs run
        if (k0 + 32 < K) {
#pragma unroll
            for (int jj = 0; jj < 4; ++jj) {
                abuf[jj] = *(const float4*)&A[(size_t)(row0 + jj * 32 + lrow) * K + k0 + 32 + lcol];
                wbuf[jj] = *(const float4*)&W[(size_t)(col0 + jj * 32 + lrow) * K + k0 + 32 + lcol];
            }
        }

        const int fr = lane & 15, koff = (lane >> 4) * 8;
        bf16x8 ahi[4], alo[4], whi[4], wlo[4];
#pragma unroll
        for (int i = 0; i < 4; ++i) {
            ahi[i] = *(const bf16x8*)&lds.Ahi[wr * 64 + i * 16 + fr][koff];
            alo[i] = *(const bf16x8*)&lds.Alo[wr * 64 + i * 16 + fr][koff];
        }
#pragma unroll
        for (int j = 0; j < 4; ++j) {
            whi[j] = *(const bf16x8*)&lds.Whi[wc * 64 + j * 16 + fr][koff];
            wlo[j] = *(const bf16x8*)&lds.Wlo[wc * 64 + j * 16 + fr][koff];
        }
#pragma unroll
        for (int i = 0; i < 4; ++i)
#pragma unroll
            for (int j = 0; j < 4; ++j) {
                acc[i][j] = __builtin_amdgcn_mfma_f32_16x16x32_bf16(alo[i], whi[j], acc[i][j], 0, 0, 0);
                acc[i][j] = __builtin_amdgcn_mfma_f32_16x16x32_bf16(ahi[i], wlo[j], acc[i][j], 0, 0, 0);
                acc[i][j] = __builtin_amdgcn_mfma_f32_16x16x32_bf16(ahi[i], whi[j], acc[i][j], 0, 0, 0);
            }
        __syncthreads();
    }

    // epilogue: C/D layout col=lane&15, row=(lane>>4)*4+reg  [m89/m91]
    const int fr = lane & 15, rg = (lane >> 4) * 4;
#pragma unroll
    for (int j = 0; j < 4; ++j) {
        const int col = col0 + wc * 64 + j * 16 + fr;
        const float bv = bias[col];
#pragma unroll
        for (int i = 0; i < 4; ++i) {
#pragma unroll
            for (int r = 0; r < 4; ++r) {
                const int row = row0 + wr * 64 + i * 16 + rg + r;
                float v = acc[i][j][r] + bv;
                if (doRelu) v = fmaxf(v, 0.f);
                C[(size_t)row * Nn + col] = v;
            }
        }
    }
}

// ------------------------------------------------------ residual + layernorm ---
__global__ __launch_bounds__(256) void ln_residual(const float* __restrict__ A,
                                                   const float* __restrict__ R,
                                                   const float* __restrict__ g,
                                                   const float* __restrict__ b,
                                                   float* __restrict__ O) {
    const int row = blockIdx.x;
    const int tid = threadIdx.x;
    float v = A[row * 256 + tid] + R[row * 256 + tid];
    float s = v, sq = v * v;
#pragma unroll
    for (int off = 32; off > 0; off >>= 1) {
        s += __shfl_down(s, off, 64);
        sq += __shfl_down(sq, off, 64);
    }
    __shared__ float ss[4], ssq[4];
    const int wave = tid >> 6, lane = tid & 63;
    if (lane == 0) { ss[wave] = s; ssq[wave] = sq; }
    __syncthreads();
    float S = ss[0] + ss[1] + ss[2] + ss[3];
    float SQ = ssq[0] + ssq[1] + ssq[2] + ssq[3];
    float mean = S * (1.0f / 256.0f);
    float var = SQ * (1.0f / 256.0f) - mean * mean;
    float inv = rsqrtf(var + 1e-5f);
    O[row * 256 + tid] = (v - mean) * inv * g[tid] + b[tid];
}

// ---------------------------------------------------------------- head GEMM ---
// z[head][n][j] = sum_d flat[n,d] * W1[j,d]. Grid 2048 = 128 j-tiles x 16 d-chunks.
__global__ __launch_bounds__(256) void head_gemm(const float* __restrict__ h,
                                                 const float* __restrict__ eW1,
                                                 const float* __restrict__ aW1,
                                                 float* __restrict__ zraw) {
    const int bx = blockIdx.x;
    const int jt = bx >> 4;        // 0..127
    const int chunk = bx & 15;
    const int jj0 = jt * 4;        // 0..508
    const int head = jj0 >> 8;
    const int jl0 = jj0 & 255;
    const float* W = (head ? aW1 : eW1) + (size_t)jl0 * D_;
    const int tid = threadIdx.x;

    float acc[4][16];
#pragma unroll
    for (int jb = 0; jb < 4; ++jb)
#pragma unroll
        for (int n = 0; n < 16; ++n) acc[jb][n] = 0.f;

    for (int s = 0; s < 16; ++s) {
        const int d4 = chunk * 16384 + s * 1024 + tid * 4;
        const int tf = d4 >> 2;     // = t*F + f
        float4 wv[4];
#pragma unroll
        for (int jb = 0; jb < 4; ++jb)
            wv[jb] = *(const float4*)(W + (size_t)jb * D_ + d4);
#pragma unroll
        for (int c = 0; c < 4; ++c) {
            const float* hp = h + c * 1048576 + tf;
            float fl[16];
#pragma unroll
            for (int n = 0; n < 16; ++n) fl[n] = hp[n * 65536];
#pragma unroll
            for (int jb = 0; jb < 4; ++jb) {
                const float w = (&wv[jb].x)[c];
#pragma unroll
                for (int n = 0; n < 16; ++n) acc[jb][n] += w * fl[n];
            }
        }
    }

    const int lane = tid & 63;
#pragma unroll
    for (int jb = 0; jb < 4; ++jb) {
#pragma unroll
        for (int n = 0; n < 16; ++n) {
            float v = acc[jb][n];
            v += __shfl_down(v, 32, 64);
            v += __shfl_down(v, 16, 64);
            v += __shfl_down(v, 8, 64);
            v += __shfl_down(v, 4, 64);
            v += __shfl_down(v, 2, 64);
            v += __shfl_down(v, 1, 64);
            if (lane == 0)
                atomicAdd(&zraw[head * 4096 + n * 256 + jl0 + jb], v);
        }
    }
}

__global__ __launch_bounds__(256) void zero_kernel(float* __restrict__ p) {
    p[blockIdx.x * 256 + threadIdx.x] = 0.f;
}

// ---------------------------------------------------------------- head MLP ---
__global__ __launch_bounds__(256) void mlp_head(const float* __restrict__ zr,
                                                const float* __restrict__ b1,
                                                const float* __restrict__ g,
                                                const float* __restrict__ bt,
                                                const float* __restrict__ W2,
                                                const float* __restrict__ b2,
                                                const float* __restrict__ W3,
                                                const float* __restrict__ b3,
                                                const float* __restrict__ W4,
                                                float* __restrict__ out,
                                                float lo, float hi, int coff) {
    __shared__ float za[256], zb[256];
    const int n = blockIdx.x, j = threadIdx.x;
    float z = zr[n * 256 + j] + b1[j];
    z = z * 0.99999500003749969f * g[j] + bt[j];   // 1/sqrt(1+1e-5)
    za[j] = fmaxf(z, 0.f);
    __syncthreads();
    float a = b2[j];
    for (int e = 0; e < 256; ++e) a += za[e] * W2[j * 256 + e];
    zb[j] = fmaxf(a, 0.f);
    __syncthreads();
    a = b3[j];
    for (int e = 0; e < 256; ++e) a += zb[e] * W3[j * 256 + e];
    za[j] = fmaxf(a, 0.f);
    __syncthreads();
    if (j < 2) {
        float v = 0.f;
        for (int e = 0; e < 256; ++e) v += za[e] * W4[j * 256 + e];
        v = fminf(fmaxf(v, lo), hi);
        out[n * 4 + 2 * j + coff] = v;
    }
}

// ---------------------------------------------------------------- launcher ---
extern "C" void kernel_launch(void* const* d_in, const int* in_sizes, int n_in,
                              void* d_out, int out_size, void* d_ws, size_t ws_size,
                              hipStream_t stream) {
    const float* x     = (const float*)d_in[0];
    const float* Wq    = (const float*)d_in[1];
    const float* Wk    = (const float*)d_in[2];
    const float* Wv    = (const float*)d_in[3];
    const float* Wo    = (const float*)d_in[4];
    const float* bo    = (const float*)d_in[5];
    const float* ln1g  = (const float*)d_in[6];
    const float* ln1b  = (const float*)d_in[7];
    const float* ln2g  = (const float*)d_in[8];
    const float* ln2b  = (const float*)d_in[9];
    const float* ffW1  = (const float*)d_in[10];
    const float* ffb1  = (const float*)d_in[11];
    const float* ffW2  = (const float*)d_in[12];
    const float* ffb2  = (const float*)d_in[13];
    const float* eW1   = (const float*)d_in[14];
    const float* eb1   = (const float*)d_in[15];
    const float* eg    = (const float*)d_in[16];
    const float* ebt   = (const float*)d_in[17];
    const float* eW2   = (const float*)d_in[18];
    const float* eb2   = (const float*)d_in[19];
    const float* eW3   = (const float*)d_in[20];
    const float* eb3   = (const float*)d_in[21];
    const float* eW4   = (const float*)d_in[22];
    const float* aW1   = (const float*)d_in[23];
    const float* ab1   = (const float*)d_in[24];
    const float* ag    = (const float*)d_in[25];
    const float* abt   = (const float*)d_in[26];
    const float* aW2   = (const float*)d_in[27];
    const float* ab2   = (const float*)d_in[28];
    const float* aW3   = (const float*)d_in[29];
    const float* ab3   = (const float*)d_in[30];
    const float* aW4   = (const float*)d_in[31];
    float* out = (float*)d_out;

    float* ws   = (float*)d_ws;
    float* h    = ws;                    // 4 Mi floats
    float* ao   = ws + 4194304;
    float* tmp  = ws + 8388608;
    float* x1   = ws + 12582912;
    float* ff1  = ws + 16777216;         // 16 Mi floats
    float* zraw = ws + 33554432;         // 8192 floats

    build_h<<<16384, 256, 0, stream>>>(x, h);

    for (int l = 0; l < 6; ++l) {
        attn_kernel<<<512, 256, 0, stream>>>(h, Wq + l * 1024, Wk + l * 1024,
                                             Wv + l * 1024, ao);
        gemm_mfma<<<dim3(2, 128), 256, 0, stream>>>(ao, Wo + l * 65536, bo + l * 256,
                                                    tmp, M_, 256, 256, 0);
        ln_residual<<<16384, 256, 0, stream>>>(tmp, h, ln1g + l * 256, ln1b + l * 256, x1);
        gemm_mfma<<<dim3(8, 128), 256, 0, stream>>>(x1, ffW1 + l * 262144, ffb1 + l * 1024,
                                                    ff1, M_, 1024, 256, 1);
        gemm_mfma<<<dim3(2, 128), 256, 0, stream>>>(ff1, ffW2 + l * 262144, ffb2 + l * 256,
                                                    tmp, M_, 256, 1024, 0);
        ln_residual<<<16384, 256, 0, stream>>>(tmp, x1, ln2g + l * 256, ln2b + l * 256, h);
    }

    zero_kernel<<<32, 256, 0, stream>>>(zraw);
    head_gemm<<<2048, 256, 0, stream>>>(h, eW1, aW1, zraw);

    const float pi = 3.14159265358979323846f;
    mlp_head<<<16, 256, 0, stream>>>(zraw, eb1, eg, ebt, eW2, eb2, eW3, eb3, eW4,
                                     out, -pi / 4.f, pi / 2.f, 0);
    mlp_head<<<16, 256, 0, stream>>>(zraw + 4096, ab1, ag, abt, aW2, ab2, aW3, ab3, aW4,
                                     out, 0.f, 2.f * pi, 1);
}